// Round 1
// baseline (333.468 us; speedup 1.0000x reference)
//
#include <hip/hip_runtime.h>
#include <math.h>
#include <float.h>

// Problem constants
#define NTOK 65536
#define NCB  4
#define MCODE 512
#define DIM  64

#define QST_SIZE (NTOK * NCB * DIM)        // 16777216
#define IDX_OFF  (QST_SIZE + 3)            // 16777219

// Tiles
#define TOK_TILE  128
#define CODE_TILE 128
#define LDS_STRIDE 68                      // 64 + 4 pad, keeps float4 alignment

// ws layout: e2 float[2048] @0 ; counts int[2048] @8192 ; lossSum float @16384

__global__ __launch_bounds__(256) void prep_kernel(const float* __restrict__ emb,
                                                   float* __restrict__ e2,
                                                   int* __restrict__ counts,
                                                   float* __restrict__ lossSum) {
    int t = blockIdx.x * 256 + threadIdx.x;
    if (t < NCB * MCODE) {
        const float4* p = (const float4*)(emb + (size_t)t * DIM);
        float s = 0.f;
#pragma unroll
        for (int i = 0; i < DIM / 4; ++i) {
            float4 v = p[i];
            s += v.x * v.x + v.y * v.y + v.z * v.z + v.w * v.w;
        }
        e2[t] = s;
        counts[t] = 0;
        if (t == 0) *lossSum = 0.f;
    }
}

__global__ __launch_bounds__(256) void vq_main(const float* __restrict__ x,
                                               const float* __restrict__ emb,
                                               const float* __restrict__ mask,
                                               const float* __restrict__ e2,
                                               int* __restrict__ counts,
                                               float* __restrict__ lossSum,
                                               float* __restrict__ outQ,
                                               float* __restrict__ outIdx) {
    __shared__ float Xs[TOK_TILE * LDS_STRIDE];
    __shared__ float Es[CODE_TILE * LDS_STRIDE];
    __shared__ float Es2[CODE_TILE];
    __shared__ int   Is[TOK_TILE];
    __shared__ float wls[4];

    const int tid = threadIdx.x;
    const int c   = blockIdx.y;
    const int n0  = blockIdx.x * TOK_TILE;
    const int ti  = tid >> 4;    // 0..15 -> token group
    const int tj  = tid & 15;    // 0..15 -> code lane (interleaved codes)

    // ---- Load X tile: 128 tokens x 64 dims ----
#pragma unroll
    for (int i = 0; i < 8; ++i) {
        int q = tid + i * 256;
        int tok = q >> 4, d4 = q & 15;
        float4 v = *(const float4*)(x + (size_t)(n0 + tok) * (NCB * DIM) + c * DIM + d4 * 4);
        *(float4*)(Xs + tok * LDS_STRIDE + d4 * 4) = v;
    }

    float minv[8];
    int   mini[8];
#pragma unroll
    for (int u = 0; u < 8; ++u) { minv[u] = FLT_MAX; mini[u] = 0; }

    for (int ch = 0; ch < MCODE / CODE_TILE; ++ch) {
        const int mbase = ch * CODE_TILE;
        // ---- Load E chunk: 128 codes x 64 dims (contiguous in global) ----
#pragma unroll
        for (int i = 0; i < 8; ++i) {
            int q = tid + i * 256;
            int mm = q >> 4, d4 = q & 15;
            float4 v = *(const float4*)(emb + ((size_t)c * MCODE + mbase + mm) * DIM + d4 * 4);
            *(float4*)(Es + mm * LDS_STRIDE + d4 * 4) = v;
        }
        if (tid < CODE_TILE) Es2[tid] = e2[c * MCODE + mbase + tid];
        __syncthreads();

        // ---- 8x8 micro-tile GEMM over K=64 ----
        float acc[8][8];
#pragma unroll
        for (int u = 0; u < 8; ++u)
#pragma unroll
            for (int v = 0; v < 8; ++v) acc[u][v] = 0.f;

#pragma unroll
        for (int k4 = 0; k4 < DIM / 4; ++k4) {
            float4 xa[8], eb[8];
#pragma unroll
            for (int u = 0; u < 8; ++u)
                xa[u] = *(const float4*)(Xs + (ti * 8 + u) * LDS_STRIDE + k4 * 4);
#pragma unroll
            for (int v = 0; v < 8; ++v)
                eb[v] = *(const float4*)(Es + (v * 16 + tj) * LDS_STRIDE + k4 * 4);
#pragma unroll
            for (int u = 0; u < 8; ++u)
#pragma unroll
                for (int v = 0; v < 8; ++v) {
                    acc[u][v] = fmaf(xa[u].x, eb[v].x, acc[u][v]);
                    acc[u][v] = fmaf(xa[u].y, eb[v].y, acc[u][v]);
                    acc[u][v] = fmaf(xa[u].z, eb[v].z, acc[u][v]);
                    acc[u][v] = fmaf(xa[u].w, eb[v].w, acc[u][v]);
                }
        }

        // ---- distances d = e2 - 2*xe ; running argmin (m ascending within thread) ----
#pragma unroll
        for (int v = 0; v < 8; ++v) {
            int   mg = mbase + v * 16 + tj;
            float ev = Es2[v * 16 + tj];
#pragma unroll
            for (int u = 0; u < 8; ++u) {
                float dv = ev - 2.f * acc[u][v];
                if (dv < minv[u]) { minv[u] = dv; mini[u] = mg; }
            }
        }
        __syncthreads();   // before next chunk overwrites Es
    }

    // ---- reduce (val,idx) across the 16 tj lanes (butterfly, first-min tie-break) ----
#pragma unroll
    for (int off = 1; off < 16; off <<= 1) {
#pragma unroll
        for (int u = 0; u < 8; ++u) {
            float ov = __shfl_xor(minv[u], off);
            int   oi = __shfl_xor(mini[u], off);
            if (ov < minv[u] || (ov == minv[u] && oi < mini[u])) {
                minv[u] = ov; mini[u] = oi;
            }
        }
    }
    if (tj == 0) {
#pragma unroll
        for (int u = 0; u < 8; ++u) Is[ti * 8 + u] = mini[u];
    }
    __syncthreads();

    // ---- indices + histogram ----
    if (tid < TOK_TILE) {
        int idx = Is[tid];
        atomicAdd(&counts[c * MCODE + idx], 1);
        outIdx[(size_t)(n0 + tid) * NCB + c] = (float)idx;
    }

    // ---- quantized_st + loss ----
    float lloss = 0.f;
#pragma unroll
    for (int i = 0; i < 8; ++i) {
        int q = tid + i * 256;
        int tok = q >> 4, d4 = q & 15;
        int idx = Is[tok];
        float mv = mask[(size_t)(n0 + tok) * NCB + c];
        float4 e4 = *(const float4*)(emb + ((size_t)c * MCODE + idx) * DIM + d4 * 4);
        float4 x4 = *(const float4*)(Xs + tok * LDS_STRIDE + d4 * 4);
        float qx = e4.x * mv, qy = e4.y * mv, qz = e4.z * mv, qw = e4.w * mv;
        float4 o;
        o.x = x4.x + (qx - x4.x);
        o.y = x4.y + (qy - x4.y);
        o.z = x4.z + (qz - x4.z);
        o.w = x4.w + (qw - x4.w);
        *(float4*)(outQ + (size_t)(n0 + tok) * (NCB * DIM) + c * DIM + d4 * 4) = o;
        float dx = x4.x - qx, dy = x4.y - qy, dz = x4.z - qz, dw = x4.w - qw;
        lloss += dx * dx + dy * dy + dz * dz + dw * dw;
    }
    // wave butterfly reduce (64 lanes)
#pragma unroll
    for (int off = 32; off > 0; off >>= 1) lloss += __shfl_xor(lloss, off);
    if ((tid & 63) == 0) wls[tid >> 6] = lloss;
    __syncthreads();
    if (tid == 0) {
        float s = wls[0] + wls[1] + wls[2] + wls[3];
        atomicAdd(lossSum, s);
    }
}

__global__ __launch_bounds__(256) void finalize_kernel(const int* __restrict__ counts,
                                                       const float* __restrict__ lossSum,
                                                       float* __restrict__ out) {
    __shared__ float wls[4];
    int tid = threadIdx.x;
    float s = 0.f;
#pragma unroll
    for (int i = 0; i < 8; ++i) {
        int j = tid + i * 256;
        float p = (float)counts[j] * (1.0f / 65536.0f);
        s += p * logf(p + 1e-10f);
    }
#pragma unroll
    for (int off = 32; off > 0; off >>= 1) s += __shfl_xor(s, off);
    if ((tid & 63) == 0) wls[tid >> 6] = s;
    __syncthreads();
    if (tid == 0) {
        float tot = wls[0] + wls[1] + wls[2] + wls[3];
        float L = *lossSum * (1.0f / (float)QST_SIZE);
        out[QST_SIZE + 0] = 0.25f * L;   // commitment_loss
        out[QST_SIZE + 1] = L;           // codebook_loss
        out[QST_SIZE + 2] = expf(-tot);  // perplexity
    }
}

extern "C" void kernel_launch(void* const* d_in, const int* in_sizes, int n_in,
                              void* d_out, int out_size, void* d_ws, size_t ws_size,
                              hipStream_t stream) {
    const float* x    = (const float*)d_in[0];
    const float* emb  = (const float*)d_in[1];
    const float* mask = (const float*)d_in[2];
    float* out = (float*)d_out;

    float* e2      = (float*)d_ws;
    int*   counts  = (int*)((char*)d_ws + 8192);
    float* lossSum = (float*)((char*)d_ws + 16384);

    prep_kernel<<<dim3(8), dim3(256), 0, stream>>>(emb, e2, counts, lossSum);
    vq_main<<<dim3(NTOK / TOK_TILE, NCB), dim3(256), 0, stream>>>(
        x, emb, mask, e2, counts, lossSum, out, out + IDX_OFF);
    finalize_kernel<<<dim3(1), dim3(256), 0, stream>>>(counts, lossSum, out);
}

// Round 2
// 222.310 us; speedup vs baseline: 1.5000x; 1.5000x over previous
//
#include <hip/hip_runtime.h>
#include <math.h>
#include <float.h>

// Problem constants
#define NTOK 65536
#define NCB  4
#define MCODE 512
#define DIM  64

#define QST_SIZE (NTOK * NCB * DIM)        // 16777216
#define IDX_OFF  (QST_SIZE + 3)            // 16777219

// Tiles
#define TOK_TILE  256                      // tokens per block (64 per wave)
#define XS_STRIDE 68                       // fp32 LDS stride: 68%32=4 -> 2-way alias (free)

// ws layout (bytes):
//   eh  f16[2048*64]  @ 0        (262144)   hi half of 512*e
//   el  f16[2048*64]  @ 262144   (262144)   lo half
//   d0  f32[2048]     @ 524288   (8192)     512 * sum(e^2)
//   counts int[2048]  @ 532480   (8192)
//   lossSum f32       @ 540672
#define WS_EH 0
#define WS_EL 262144
#define WS_D0 524288
#define WS_CNT 532480
#define WS_LOSS 540672

typedef _Float16 half8 __attribute__((ext_vector_type(8)));
typedef float floatx4 __attribute__((ext_vector_type(4)));

// ---- prep: f16 hi/lo split of 512*e, d0 = 512*|e|^2, zero counts/loss ----
__global__ __launch_bounds__(256) void prep_kernel(const float* __restrict__ emb,
                                                   _Float16* __restrict__ eh,
                                                   _Float16* __restrict__ el,
                                                   float* __restrict__ d0,
                                                   int* __restrict__ counts,
                                                   float* __restrict__ lossSum) {
    int row = blockIdx.x * 256 + threadIdx.x;   // 0..2047  (grid=8)
    if (row >= NCB * MCODE) return;
    const float* src = emb + (size_t)row * DIM;
    _Float16* ph = eh + (size_t)row * DIM;
    _Float16* pl = el + (size_t)row * DIM;
    float s = 0.f;
#pragma unroll
    for (int j = 0; j < DIM / 8; ++j) {
        half8 h, l;
#pragma unroll
        for (int t = 0; t < 8; ++t) {
            float e = src[j * 8 + t];
            s += e * e;
            float f = e * 512.0f;
            _Float16 hi = (_Float16)f;
            float r = f - (float)hi;
            h[t] = hi;
            l[t] = (_Float16)r;
        }
        *(half8*)(ph + j * 8) = h;
        *(half8*)(pl + j * 8) = l;
    }
    d0[row] = 512.0f * s;
    counts[row] = 0;
    if (row == 0) *lossSum = 0.f;
}

// ---- main: MFMA distances + argmin + epilogue ----
__global__ __launch_bounds__(256) void vq_main(const float* __restrict__ x,
                                               const float* __restrict__ emb,
                                               const float* __restrict__ mask,
                                               const _Float16* __restrict__ eh,
                                               const _Float16* __restrict__ el,
                                               const float* __restrict__ d0,
                                               int* __restrict__ counts,
                                               float* __restrict__ lossSum,
                                               float* __restrict__ outQ,
                                               float* __restrict__ outIdx) {
    __shared__ float Xs[TOK_TILE * XS_STRIDE];   // 69632 B
    __shared__ int   Is[TOK_TILE];
    __shared__ float wls[4];

    const int tid  = threadIdx.x;
    const int c    = blockIdx.y;
    const int n0tk = blockIdx.x * TOK_TILE;
    const int lane = tid & 63;
    const int w    = tid >> 6;            // wave id 0..3
    const int col  = lane & 15;           // MFMA col (code within tile) / row m in A
    const int quad = lane >> 4;           // 0..3

    // ---- stage X tile: 256 tokens x 64 dims fp32, coalesced ----
#pragma unroll
    for (int i = 0; i < 16; ++i) {
        int q = tid + i * 256;
        int tok = q >> 4, d4 = q & 15;
        float4 v = *(const float4*)(x + (size_t)(n0tk + tok) * (NCB * DIM) + c * DIM + d4 * 4);
        *(float4*)(Xs + tok * XS_STRIDE + d4 * 4) = v;
    }
    __syncthreads();

    // ---- build persistent A fragments (hi/lo) for this wave's 64 tokens ----
    // subtile s: tokens w*64 + s*16 + col ; kstep ks: k = ks*32 + quad*8 + j
    half8 Ahi[4][2], Alo[4][2];
#pragma unroll
    for (int s = 0; s < 4; ++s) {
        const float* xr = Xs + (w * 64 + s * 16 + col) * XS_STRIDE;
#pragma unroll
        for (int ks = 0; ks < 2; ++ks) {
            const float* p = xr + ks * 32 + quad * 8;
            half8 h, l;
#pragma unroll
            for (int t = 0; t < 8; ++t) {
                float f = p[t];
                _Float16 hi = (_Float16)f;
                float r = f - (float)hi;
                h[t] = hi;
                l[t] = (_Float16)r;
            }
            Ahi[s][ks] = h;
            Alo[s][ks] = l;
        }
    }

    float minv[4][4];
    int   mini[4][4];
#pragma unroll
    for (int s = 0; s < 4; ++s)
#pragma unroll
        for (int r = 0; r < 4; ++r) { minv[s][r] = FLT_MAX; mini[s][r] = 0; }

    const _Float16* ehc = eh + (size_t)c * MCODE * DIM;
    const _Float16* elc = el + (size_t)c * MCODE * DIM;
    const float*    d0c = d0 + c * MCODE;

    // ---- sweep 32 n-tiles of 16 codes ----
#pragma unroll 2
    for (int nt = 0; nt < 32; ++nt) {
        const int nbase = nt * 16;
        const int n = nbase + col;
        const _Float16* bh = ehc + (size_t)n * DIM + quad * 8;
        const _Float16* bl = elc + (size_t)n * DIM + quad * 8;
        half8 Bh0 = *(const half8*)(bh);
        half8 Bh1 = *(const half8*)(bh + 32);
        half8 Bl0 = *(const half8*)(bl);
        half8 Bl1 = *(const half8*)(bl + 32);
        float d0v = d0c[n];

#pragma unroll
        for (int s = 0; s < 4; ++s) {
            floatx4 acc = {0.f, 0.f, 0.f, 0.f};
            acc = __builtin_amdgcn_mfma_f32_16x16x32_f16(Ahi[s][0], Bh0, acc, 0, 0, 0);
            acc = __builtin_amdgcn_mfma_f32_16x16x32_f16(Ahi[s][1], Bh1, acc, 0, 0, 0);
            acc = __builtin_amdgcn_mfma_f32_16x16x32_f16(Alo[s][0], Bh0, acc, 0, 0, 0);
            acc = __builtin_amdgcn_mfma_f32_16x16x32_f16(Alo[s][1], Bh1, acc, 0, 0, 0);
            acc = __builtin_amdgcn_mfma_f32_16x16x32_f16(Ahi[s][0], Bl0, acc, 0, 0, 0);
            acc = __builtin_amdgcn_mfma_f32_16x16x32_f16(Ahi[s][1], Bl1, acc, 0, 0, 0);
#pragma unroll
            for (int r = 0; r < 4; ++r) {
                float dv = fmaf(-2.f, acc[r], d0v);   // alpha*(e2 - 2 x.e)
                if (dv < minv[s][r]) { minv[s][r] = dv; mini[s][r] = n; }
            }
        }
    }

    // ---- reduce across the 16 col-lanes of each quad (first-min tie-break) ----
#pragma unroll
    for (int off = 1; off < 16; off <<= 1) {
#pragma unroll
        for (int s = 0; s < 4; ++s)
#pragma unroll
            for (int r = 0; r < 4; ++r) {
                float ov = __shfl_xor(minv[s][r], off);
                int   oi = __shfl_xor(mini[s][r], off);
                if (ov < minv[s][r] || (ov == minv[s][r] && oi < mini[s][r])) {
                    minv[s][r] = ov; mini[s][r] = oi;
                }
            }
    }
    if (col == 0) {
        // rows for subtile s: token = w*64 + s*16 + quad*4 + r
#pragma unroll
        for (int s = 0; s < 4; ++s)
#pragma unroll
            for (int r = 0; r < 4; ++r)
                Is[w * 64 + s * 16 + quad * 4 + r] = mini[s][r];
    }
    __syncthreads();

    // ---- indices + histogram ----
    {
        int idx = Is[tid];
        atomicAdd(&counts[c * MCODE + idx], 1);
        outIdx[(size_t)(n0tk + tid) * NCB + c] = (float)idx;
    }

    // ---- quantized_st + loss (original fp32 emb for exactness) ----
    float lloss = 0.f;
#pragma unroll
    for (int i = 0; i < 16; ++i) {
        int q = tid + i * 256;
        int tok = q >> 4, d4 = q & 15;
        int idx = Is[tok];
        float mv = mask[(size_t)(n0tk + tok) * NCB + c];
        float4 e4 = *(const float4*)(emb + ((size_t)c * MCODE + idx) * DIM + d4 * 4);
        float4 x4 = *(const float4*)(Xs + tok * XS_STRIDE + d4 * 4);
        float qx = e4.x * mv, qy = e4.y * mv, qz = e4.z * mv, qw = e4.w * mv;
        float4 o;
        o.x = x4.x + (qx - x4.x);
        o.y = x4.y + (qy - x4.y);
        o.z = x4.z + (qz - x4.z);
        o.w = x4.w + (qw - x4.w);
        *(float4*)(outQ + (size_t)(n0tk + tok) * (NCB * DIM) + c * DIM + d4 * 4) = o;
        float dx = x4.x - qx, dy = x4.y - qy, dz = x4.z - qz, dw = x4.w - qw;
        lloss += dx * dx + dy * dy + dz * dz + dw * dw;
    }
#pragma unroll
    for (int off = 32; off > 0; off >>= 1) lloss += __shfl_xor(lloss, off);
    if ((tid & 63) == 0) wls[tid >> 6] = lloss;
    __syncthreads();
    if (tid == 0) {
        float s = wls[0] + wls[1] + wls[2] + wls[3];
        atomicAdd(lossSum, s);
    }
}

__global__ __launch_bounds__(256) void finalize_kernel(const int* __restrict__ counts,
                                                       const float* __restrict__ lossSum,
                                                       float* __restrict__ out) {
    __shared__ float wls[4];
    int tid = threadIdx.x;
    float s = 0.f;
#pragma unroll
    for (int i = 0; i < 8; ++i) {
        int j = tid + i * 256;
        float p = (float)counts[j] * (1.0f / 65536.0f);
        s += p * logf(p + 1e-10f);
    }
#pragma unroll
    for (int off = 32; off > 0; off >>= 1) s += __shfl_xor(s, off);
    if ((tid & 63) == 0) wls[tid >> 6] = s;
    __syncthreads();
    if (tid == 0) {
        float tot = wls[0] + wls[1] + wls[2] + wls[3];
        float L = *lossSum * (1.0f / (float)QST_SIZE);
        out[QST_SIZE + 0] = 0.25f * L;   // commitment_loss
        out[QST_SIZE + 1] = L;           // codebook_loss
        out[QST_SIZE + 2] = expf(-tot);  // perplexity
    }
}

extern "C" void kernel_launch(void* const* d_in, const int* in_sizes, int n_in,
                              void* d_out, int out_size, void* d_ws, size_t ws_size,
                              hipStream_t stream) {
    const float* x    = (const float*)d_in[0];
    const float* emb  = (const float*)d_in[1];
    const float* mask = (const float*)d_in[2];
    float* out = (float*)d_out;

    _Float16* eh   = (_Float16*)((char*)d_ws + WS_EH);
    _Float16* el   = (_Float16*)((char*)d_ws + WS_EL);
    float* d0      = (float*)((char*)d_ws + WS_D0);
    int*   counts  = (int*)((char*)d_ws + WS_CNT);
    float* lossSum = (float*)((char*)d_ws + WS_LOSS);

    prep_kernel<<<dim3(8), dim3(256), 0, stream>>>(emb, eh, el, d0, counts, lossSum);
    vq_main<<<dim3(NTOK / TOK_TILE, NCB), dim3(256), 0, stream>>>(
        x, emb, mask, eh, el, d0, counts, lossSum, out, out + IDX_OFF);
    finalize_kernel<<<dim3(1), dim3(256), 0, stream>>>(counts, lossSum, out);
}